// Round 3
// baseline (110.369 us; speedup 1.0000x reference)
//
#include <hip/hip_runtime.h>

// SpatialAttention G=2,N=192,D=64,H=4,DK=16 — fused f16-MFMA, round 3.
// 512 thr (8 waves) per (g,n); 80 KiB LDS -> 2 blocks/CU; K/Q fragments
// computed in-register in their consumer MFMA layout (no LDS round trip).

typedef float    f32x4 __attribute__((ext_vector_type(4)));
typedef _Float16 f16x4 __attribute__((ext_vector_type(4)));
typedef _Float16 f16x8 __attribute__((ext_vector_type(8)));

// [.][64] f16 tile, 16B blocks, XOR row&7 (b128-readable, conflict-free)
__device__ __forceinline__ int xsw64(int r, int c) {
    return (r << 6) + (((c >> 3) ^ (r & 7)) << 3) + (c & 7);
}
// [.][192] f16 tile, 16B blocks, XOR row&7
__device__ __forceinline__ int vsw192(int r, int c) {
    return r * 192 + ((((c >> 3) ^ (r & 7)) & 31) << 3) + (c & 7);
}

extern "C" __global__ void __launch_bounds__(512, 4)
spa_mfma2(const float* __restrict__ adj,
          const float* __restrict__ Wq, const float* __restrict__ bq,
          const float* __restrict__ Wk, const float* __restrict__ bk,
          const float* __restrict__ Wv, const float* __restrict__ bv,
          const float* __restrict__ Wo, const float* __restrict__ bo,
          float* __restrict__ out) {
    extern __shared__ __align__(16) char smem[];
    _Float16* X  = (_Float16*)smem;           // [192][64] xsw64 (tokens; later attn out)
    _Float16* VT = (_Float16*)smem + 12288;   // [64][192] vsw192 (V transposed)
    _Float16* WT = (_Float16*)smem + 24576;   // 4 x [64][64] xsw64 (Wq/Wk/Wv/Wo transposed)

    const int tid = threadIdx.x;
    const int l   = tid & 63;
    const int wv  = tid >> 6;    // wave 0..7
    const int l15 = l & 15;
    const int g   = l >> 4;      // 0..3

    const float* Xg   = adj + (size_t)blockIdx.x * (192 * 64);
    float*       outg = out + (size_t)blockIdx.x * (192 * 64);

    // ---------------- stage X -> f16 LDS (swizzled) ----------------
    {
        const int d0 = (tid & 7) << 3;
        const int t0 = tid >> 3;
        for (int p = 0; p < 3; ++p) {
            int t = t0 + (p << 6);
            const float4* src = (const float4*)&Xg[(t << 6) + d0];
            float4 v0 = src[0], v1 = src[1];
            f16x8 h8;
            h8[0]=(_Float16)v0.x; h8[1]=(_Float16)v0.y; h8[2]=(_Float16)v0.z; h8[3]=(_Float16)v0.w;
            h8[4]=(_Float16)v1.x; h8[5]=(_Float16)v1.y; h8[6]=(_Float16)v1.z; h8[7]=(_Float16)v1.w;
            *(f16x8*)&X[xsw64(t, d0)] = h8;
        }
    }
    // ---------------- stage W^T (all four) ----------------
    {
        const int e  = tid & 63;
        const int db = (tid >> 6) << 3;
        const float* Ws[4] = {Wq, Wk, Wv, Wo};
#pragma unroll
        for (int m = 0; m < 4; ++m) {
            f16x8 h8;
#pragma unroll
            for (int j = 0; j < 8; ++j) h8[j] = (_Float16)Ws[m][(db + j) * 64 + e];
            *(f16x8*)&WT[m * 4096 + xsw64(e, db)] = h8;
        }
    }
    __syncthreads();

    const f32x4 z = {0.f, 0.f, 0.f, 0.f};
    const int h  = wv >> 1;      // head this wave attends
    const int eh = h << 4;

    // ---------------- VT slice: head (wv&3), 6 s-tiles ----------------
    {
        const int et  = wv & 3;
        const int stb = (wv >> 2) * 6;
        f16x8 w0 = *(const f16x8*)&WT[2*4096 + xsw64((et<<4)+l15, g<<3)];
        f16x8 w1 = *(const f16x8*)&WT[2*4096 + xsw64((et<<4)+l15, 32+(g<<3))];
        f32x4 b4 = *(const f32x4*)&bv[(et<<4)+(g<<2)];
        for (int s6 = 0; s6 < 6; ++s6) {
            int st = stb + s6;
            f16x8 x0 = *(const f16x8*)&X[xsw64((st<<4)+l15, g<<3)];
            f16x8 x1 = *(const f16x8*)&X[xsw64((st<<4)+l15, 32+(g<<3))];
            f32x4 c = __builtin_amdgcn_mfma_f32_16x16x32_f16(w0, x0, z, 0,0,0);
            c = __builtin_amdgcn_mfma_f32_16x16x32_f16(w1, x1, c, 0,0,0);
            int s = (st << 4) + l15;
#pragma unroll
            for (int r = 0; r < 4; ++r)
                VT[vsw192((et<<4)+(g<<2)+r, s)] = (_Float16)(c[r] + b4[r]);
        }
    }

    // ---------------- K fragments in-register (score-MFMA A-frag layout) ------
    // K^T = Wk^T @ X^T: c[r] = K[st*16+l15][eh+g*4+r] == kf[st][r] exactly.
    f16x4 kf[12];
    {
        f16x8 w0 = *(const f16x8*)&WT[1*4096 + xsw64(eh+l15, g<<3)];
        f16x8 w1 = *(const f16x8*)&WT[1*4096 + xsw64(eh+l15, 32+(g<<3))];
        f32x4 b4 = *(const f32x4*)&bk[eh+(g<<2)];
#pragma unroll
        for (int st = 0; st < 12; ++st) {
            f16x8 x0 = *(const f16x8*)&X[xsw64((st<<4)+l15, g<<3)];
            f16x8 x1 = *(const f16x8*)&X[xsw64((st<<4)+l15, 32+(g<<3))];
            f32x4 c = __builtin_amdgcn_mfma_f32_16x16x32_f16(w0, x0, z, 0,0,0);
            c = __builtin_amdgcn_mfma_f32_16x16x32_f16(w1, x1, c, 0,0,0);
#pragma unroll
            for (int r = 0; r < 4; ++r) kf[st][r] = (_Float16)(c[r] + b4[r]);
        }
    }

    // ---------------- Q fragments in-register (score-MFMA B-frag layout) ------
    // Fold 1/sqrt(DK) * log2(e) into Q so softmax uses a single v_exp (exp2).
    f16x4 qf[6];
    const int ttb = (wv & 1) * 6;    // t-tile base (6 tiles = 96 rows)
    {
        f16x8 w0 = *(const f16x8*)&WT[0*4096 + xsw64(eh+l15, g<<3)];
        f16x8 w1 = *(const f16x8*)&WT[0*4096 + xsw64(eh+l15, 32+(g<<3))];
        f32x4 b4 = *(const f32x4*)&bq[eh+(g<<2)];
        const float qs = 0.25f * 1.4426950408889634f;
#pragma unroll
        for (int j = 0; j < 6; ++j) {
            int tt = ttb + j;
            f16x8 x0 = *(const f16x8*)&X[xsw64((tt<<4)+l15, g<<3)];
            f16x8 x1 = *(const f16x8*)&X[xsw64((tt<<4)+l15, 32+(g<<3))];
            f32x4 c = __builtin_amdgcn_mfma_f32_16x16x32_f16(w0, x0, z, 0,0,0);
            c = __builtin_amdgcn_mfma_f32_16x16x32_f16(w1, x1, c, 0,0,0);
#pragma unroll
            for (int r = 0; r < 4; ++r) qf[j][r] = (_Float16)((c[r] + b4[r]) * qs);
        }
    }
    __syncthreads();   // VT complete; X reads done (safe to overwrite X below)

    // ---------------- vf: PV-MFMA A-frags from VT ----------------
    f16x4 vf[12];
#pragma unroll
    for (int st = 0; st < 12; ++st)
        vf[st] = *(const f16x4*)&VT[vsw192(eh+l15, (st<<4)+(g<<2))];

    // ---------------- attention: 6 t-tiles, P never leaves registers ----------
    for (int j = 0; j < 6; ++j) {
        f32x4 accA = z, accB = z;
        float rsum = 0.f;
#pragma unroll
        for (int st = 0; st < 12; ++st) {
            f32x4 c = __builtin_amdgcn_mfma_f32_16x16x16f16(kf[st], qf[j], z, 0,0,0);
            float p0 = exp2f(c[0]), p1 = exp2f(c[1]);
            float p2 = exp2f(c[2]), p3 = exp2f(c[3]);
            rsum += (p0 + p1) + (p2 + p3);
            f16x4 pf;
            pf[0]=(_Float16)p0; pf[1]=(_Float16)p1; pf[2]=(_Float16)p2; pf[3]=(_Float16)p3;
            if (st & 1) accB = __builtin_amdgcn_mfma_f32_16x16x16f16(vf[st], pf, accB, 0,0,0);
            else        accA = __builtin_amdgcn_mfma_f32_16x16x16f16(vf[st], pf, accA, 0,0,0);
        }
        rsum += __shfl_xor(rsum, 16);
        rsum += __shfl_xor(rsum, 32);
        const float rinv = 1.0f / rsum;
        f16x4 o4;
#pragma unroll
        for (int r = 0; r < 4; ++r) o4[r] = (_Float16)((accA[r] + accB[r]) * rinv);
        // write attention output into dead X region (xsw64 layout)
        *(f16x4*)&X[xsw64(((ttb + j) << 4) + l15, eh + (g << 2))] = o4;
    }
    __syncthreads();

    // ---------------- O-projection -> global ----------------
    {
        const int eo = ((wv & 3) << 4) + l15;
        f16x8 w0 = *(const f16x8*)&WT[3*4096 + xsw64(eo, g<<3)];
        f16x8 w1 = *(const f16x8*)&WT[3*4096 + xsw64(eo, 32+(g<<3))];
        const float bov = bo[eo];
#pragma unroll
        for (int i = 0; i < 6; ++i) {
            int tt = (wv + (i << 3)) >> 2;
            f16x8 a0 = *(const f16x8*)&X[xsw64((tt<<4)+l15, g<<3)];
            f16x8 a1 = *(const f16x8*)&X[xsw64((tt<<4)+l15, 32+(g<<3))];
            f32x4 c = __builtin_amdgcn_mfma_f32_16x16x32_f16(a0, w0, z, 0,0,0);
            c = __builtin_amdgcn_mfma_f32_16x16x32_f16(a1, w1, c, 0,0,0);
#pragma unroll
            for (int r = 0; r < 4; ++r)
                outg[(((tt << 4) + (g << 2) + r) << 6) + eo] = c[r] + bov;
        }
    }
}

extern "C" void kernel_launch(void* const* d_in, const int* in_sizes, int n_in,
                              void* d_out, int out_size, void* d_ws, size_t ws_size,
                              hipStream_t stream) {
    (void)in_sizes; (void)n_in; (void)d_ws; (void)ws_size; (void)out_size;
    const float* adj = (const float*)d_in[0];
    const float* Wq  = (const float*)d_in[1];
    const float* bq  = (const float*)d_in[2];
    const float* Wk  = (const float*)d_in[3];
    const float* bk  = (const float*)d_in[4];
    const float* Wv  = (const float*)d_in[5];
    const float* bv  = (const float*)d_in[6];
    const float* Wo  = (const float*)d_in[7];
    const float* bo  = (const float*)d_in[8];
    float* out = (float*)d_out;

    const int shmem = 81920;  // 80 KiB: X 24K + VT 24K + WT 32K -> 2 blocks/CU
    hipFuncSetAttribute((const void*)spa_mfma2,
                        hipFuncAttributeMaxDynamicSharedMemorySize, shmem);
    spa_mfma2<<<2 * 192, 512, shmem, stream>>>(adj, Wq, bq, Wk, bk, Wv, bv, Wo, bo, out);
}